// Round 2
// baseline (980.219 us; speedup 1.0000x reference)
//
#include <hip/hip_runtime.h>
#include <math.h>

#define DEVI __device__ __forceinline__

// SGPR broadcast from a compile-time-constant (or wave-uniform) lane.
DEVI float rlane(float v, int l) {
    return __builtin_bit_cast(float, __builtin_amdgcn_readlane(__builtin_bit_cast(int, v), l));
}
DEVI float sigf(float v) { return 1.0f / (1.0f + __expf(-v)); }
DEVI float tanh_f(float v) {
    v = fminf(fmaxf(v, -15.0f), 15.0f);
    float e = __expf(2.0f * v);
    return (e - 1.0f) / (e + 1.0f);
}

// ---------------------------------------------------------------------------
// Kernel A: (b,t)-independent tables:
//   Kkk[d][e]=k_d.k_e ; Kkb[d][e]=k_d.b_e ; Kbb[d][e]=b_d.b_e ; beta normalize
// ---------------------------------------------------------------------------
__global__ void precompute_kernel(const float* __restrict__ Kg, const float* __restrict__ Bg,
                                  const float* __restrict__ betaw,
                                  float* __restrict__ Kkk, float* __restrict__ Kkb,
                                  float* __restrict__ Kbb, float* __restrict__ beta) {
    int tid = threadIdx.x;
    for (int job = blockIdx.x * 256 + tid; job < 4800; job += gridDim.x * 256) {
        int m = job / 1600;
        int r = job - m * 1600;
        int d = r / 40;
        int e = r - d * 40;
        const float* A = (m == 2) ? Bg : Kg;
        const float* B = (m == 0) ? Kg : Bg;
        float s0 = 0.0f, s1 = 0.0f;
        for (int u = 0; u < 64; u += 2) {
            s0 = fmaf(A[d * 64 + u], B[e * 64 + u], s0);
            s1 = fmaf(A[d * 64 + u + 1], B[e * 64 + u + 1], s1);
        }
        float* O = (m == 0) ? Kkk : ((m == 1) ? Kkb : Kbb);
        O[d * 40 + e] = s0 + s1;
    }
    if (blockIdx.x == 0) {
        __shared__ float red[256];
        float av = (tid < 128) ? (fabsf(betaw[tid]) + 1e-8f) : 0.0f;
        red[tid] = av;
        __syncthreads();
        for (int s = 128; s > 0; s >>= 1) {
            if (tid < s) red[tid] += red[tid + s];
            __syncthreads();
        }
        float tot = red[0];
        if (tid < 128) beta[tid] = av / tot;
    }
}

// ---------------------------------------------------------------------------
// Kernel B: one LSTM layer (gates i,f,g,o), one WG per batch row.
// Weight columns in VGPRs; input sequence staged in LDS; readlane broadcasts.
// ---------------------------------------------------------------------------
template <int DIN>
__launch_bounds__(256, 1)
__global__ void lstm_kernel(const float* __restrict__ xin, const float* __restrict__ W,
                            const float* __restrict__ U, const float* __restrict__ bvec,
                            float* __restrict__ hout) {
    int b = blockIdx.x;
    int tid = threadIdx.x;
    int lane = tid & 63;
    float wcol[DIN];
    float ucol[64];
#pragma unroll
    for (int d = 0; d < DIN; ++d) wcol[d] = W[d * 256 + tid];
#pragma unroll
    for (int k = 0; k < 64; ++k) ucol[k] = U[k * 256 + tid];
    float bj = bvec[tid];

    __shared__ float x_lds[128 * DIN];
    __shared__ float h_lds[64];
    __shared__ float a_lds[256];
    for (int i = tid; i < 128 * DIN; i += 256) x_lds[i] = xin[(size_t)b * 128 * DIN + i];
    if (tid < 64) h_lds[tid] = 0.0f;
    float c = 0.0f;
    __syncthreads();

    int li = (lane < DIN) ? lane : 0;
    for (int t = 0; t < 128; ++t) {
        float xv = x_lds[t * DIN + li];
        float hv = h_lds[lane];
        float a0 = bj, a1 = 0.0f;
#pragma unroll
        for (int d = 0; d < DIN; d += 2) {
            a0 = fmaf(rlane(xv, d), wcol[d], a0);
            a1 = fmaf(rlane(xv, d + 1), wcol[d + 1], a1);
        }
#pragma unroll
        for (int k = 0; k < 64; k += 2) {
            a0 = fmaf(rlane(hv, k), ucol[k], a0);
            a1 = fmaf(rlane(hv, k + 1), ucol[k + 1], a1);
        }
        float acc = a0 + a1;
        int g = tid >> 6;
        float a = (g == 2) ? tanh_f(acc) : sigf(acc);
        a_lds[tid] = a;
        __syncthreads();
        if (tid < 64) {
            float iv = a_lds[tid], fv = a_lds[tid + 64];
            float gv = a_lds[tid + 128], ov = a_lds[tid + 192];
            c = fmaf(fv, c, iv * gv);
            float h = ov * tanh_f(c);
            h_lds[tid] = h;
            hout[((size_t)b * 128 + t) * 64 + tid] = h;
        }
        __syncthreads();
    }
}

// ---------------------------------------------------------------------------
// Kernel C: attention. One wave per 8 (b,t): table-based G build, register GE
// solve (row-per-lane, readlane broadcasts, rcp pivots), o_hat, beta-weighted
// sum. Grid = 512 blocks x 512 threads (8 waves, 8 t each).
// ---------------------------------------------------------------------------
__launch_bounds__(512, 4)
__global__ void attn_kernel(const float* __restrict__ xin, const float* __restrict__ yin,
                            const float* __restrict__ Kg, const float* __restrict__ Bg,
                            const float* __restrict__ Kkkw, const float* __restrict__ Kkbw,
                            const float* __restrict__ Kbbw, const float* __restrict__ betap,
                            float* __restrict__ out) {
    __shared__ float sm[2600 * 2 + 1640 * 4 + 512];
    float* K_l = sm;            // [40][65]
    float* B_l = K_l + 2600;    // [40][65]
    float* kk  = B_l + 2600;    // [40][41]
    float* kbt = kk + 1640;     // [40][41]  kb^T (kb[e][d])
    float* kbr = kbt + 1640;    // [40][41]  kb
    float* bb  = kbr + 1640;    // [40][41]
    float* zred = bb + 1640;    // [512]
    int tid = threadIdx.x;
    for (int i = tid; i < 2560; i += 512) {
        int d = i >> 6, u = i & 63;
        K_l[d * 65 + u] = Kg[i];
        B_l[d * 65 + u] = Bg[i];
    }
    for (int i = tid; i < 1600; i += 512) {
        int d = i / 40, e = i - d * 40;
        kk[d * 41 + e] = Kkkw[i];
        kbr[d * 41 + e] = Kkbw[i];
        kbt[d * 41 + e] = Kkbw[e * 40 + d];
        bb[d * 41 + e] = Kbbw[i];
    }
    __syncthreads();

    int b = blockIdx.x >> 1;
    int hb = blockIdx.x & 1;
    int wv = tid >> 6;
    int lane = tid & 63;
    int rl0 = (lane < 40) ? lane : 39;
    const float* Krow = K_l + rl0 * 65;
    const float* Brow = B_l + rl0 * 65;
    const float* kkrow = kk + rl0 * 41;
    const float* kbtrow = kbt + rl0 * 41;
    const float* kbrrow = kbr + rl0 * 41;
    const float* bbrow = bb + rl0 * 41;

    float zacc = 0.0f;
    int t0 = hb * 64 + wv * 8;
    size_t bt0 = (size_t)b * 128 + t0;
    float xp = xin[bt0 * 40 + rl0];
    float yp = yin[bt0 * 64 + lane];

#pragma unroll 1
    for (int it = 0; it < 8; ++it) {
        float xv = (lane < 40) ? xp : 0.0f;
        float yv = yp;
        float betat = betap[t0 + it];
        if (it < 7) {
            size_t btn = bt0 + it + 1;
            xp = xin[btn * 40 + rl0];
            yp = yin[btn * 64 + lane];
        }

        // t1 = (K y)_d, t2 = (B y)_d   (lane = row d)
        float t1a = 0.0f, t1b = 0.0f, t2a = 0.0f, t2b = 0.0f;
#pragma unroll
        for (int u = 0; u < 64; u += 2) {
            float y0 = rlane(yv, u);
            float y1 = rlane(yv, u + 1);
            t1a = fmaf(Krow[u], y0, t1a);
            t1b = fmaf(Krow[u + 1], y1, t1b);
            t2a = fmaf(Brow[u], y0, t2a);
            t2b = fmaf(Brow[u + 1], y1, t2b);
        }

        // Augmented row: A[e] = G[d][e], A[40] = XTy_d
        float A[41];
        A[40] = fmaf(xv, t1a + t1b, t2a + t2b);
#pragma unroll
        for (int e = 0; e < 40; ++e) {
            float sxe = rlane(xv, e);
            float f1 = fmaf(xv, kkrow[e], kbtrow[e]);
            float f2 = fmaf(xv, kbrrow[e], bbrow[e]);
            A[e] = fmaf(sxe, f1, f2);
        }

        // GE forward elimination, rcp pivots, save per-lane pivot reciprocal
        float rpl = 0.0f;
#pragma unroll
        for (int k = 0; k < 40; ++k) {
            float piv = rlane(A[k], k);
            float rp = __builtin_amdgcn_rcpf(piv);
            rpl = (lane == k) ? rp : rpl;
            float m = (lane > k) ? A[k] * rp : 0.0f;
#pragma unroll
            for (int j = k + 1; j <= 40; ++j) {
                A[j] = fmaf(-m, rlane(A[j], k), A[j]);
            }
        }

        // Back substitution (division-free)
        float acc = A[40];
        float alpha = 0.0f;
#pragma unroll
        for (int k = 39; k >= 0; --k) {
            float xk = rlane(acc, k) * rlane(rpl, k);
            alpha = (lane == k) ? xk : alpha;
            acc = fmaf(-xk, A[k], acc);
        }

        // o_hat[u] = sum_d (alpha_d x_d) K[d][u] + alpha_d B[d][u]  (lane = u)
        float w = alpha * xv;
        float oha = 0.0f, ohb = 0.0f;
#pragma unroll
        for (int d = 0; d < 40; d += 2) {
            float sw0 = rlane(w, d), sa0 = rlane(alpha, d);
            float sw1 = rlane(w, d + 1), sa1 = rlane(alpha, d + 1);
            oha = fmaf(sw0, K_l[d * 65 + lane], oha);
            oha = fmaf(sa0, B_l[d * 65 + lane], oha);
            ohb = fmaf(sw1, K_l[(d + 1) * 65 + lane], ohb);
            ohb = fmaf(sa1, B_l[(d + 1) * 65 + lane], ohb);
        }
        zacc = fmaf(betat, oha + ohb, zacc);
    }

    zred[tid] = zacc;
    __syncthreads();
    if (tid < 256) zred[tid] += zred[tid + 256];
    __syncthreads();
    if (tid < 128) zred[tid] += zred[tid + 128];
    __syncthreads();
    if (tid < 64) {
        float s = zred[tid] + zred[tid + 64];
        atomicAdd(&out[b * 64 + tid], s);  // 2 blocks per b -> order-invariant
    }
}

// ---------------------------------------------------------------------------
extern "C" void kernel_launch(void* const* d_in, const int* in_sizes, int n_in,
                              void* d_out, int out_size, void* d_ws, size_t ws_size,
                              hipStream_t stream) {
    const float* x  = (const float*)d_in[0];
    const float* W0 = (const float*)d_in[1];
    const float* U0 = (const float*)d_in[2];
    const float* b0 = (const float*)d_in[3];
    const float* W1 = (const float*)d_in[4];
    const float* U1 = (const float*)d_in[5];
    const float* b1 = (const float*)d_in[6];
    const float* Kg = (const float*)d_in[7];
    const float* Bg = (const float*)d_in[8];
    const float* bw = (const float*)d_in[9];
    float* out = (float*)d_out;

    float* h0   = (float*)d_ws;              // 256*128*64 f32
    float* y    = h0 + 256 * 128 * 64;       // 256*128*64 f32
    float* Kkk  = y + 256 * 128 * 64;        // 1600
    float* Kkb  = Kkk + 1600;                // 1600
    float* Kbb  = Kkb + 1600;                // 1600
    float* beta = Kbb + 1600;                // 128

    hipMemsetAsync(d_out, 0, (size_t)out_size * sizeof(float), stream);
    precompute_kernel<<<5, 256, 0, stream>>>(Kg, Bg, bw, Kkk, Kkb, Kbb, beta);
    lstm_kernel<40><<<256, 256, 0, stream>>>(x, W0, U0, b0, h0);
    lstm_kernel<64><<<256, 256, 0, stream>>>(h0, W1, U1, b1, y);
    attn_kernel<<<512, 512, 0, stream>>>(x, y, Kg, Bg, Kkk, Kkb, Kbb, beta, out);
}

// Round 3
// 669.510 us; speedup vs baseline: 1.4641x; 1.4641x over previous
//
#include <hip/hip_runtime.h>
#include <math.h>

#define DEVI __device__ __forceinline__

// SGPR broadcast from a compile-time-constant (or uniform) lane.
DEVI float rlane(float v, int l) {
    return __builtin_bit_cast(float, __builtin_amdgcn_readlane(__builtin_bit_cast(int, v), l));
}
DEVI float sigf(float v) { return 1.0f / (1.0f + __expf(-v)); }
DEVI float tanh_f(float v) {
    v = fminf(fmaxf(v, -15.0f), 15.0f);
    float e = __expf(2.0f * v);
    return (e - 1.0f) / (e + 1.0f);
}

// ---------------------------------------------------------------------------
// Kernel A: fused (b,t)-independent tables.
//   Qg[d][e]  = {kk[d][e], kb[e][d], kb[d][e], bb[d][e]}   (1600 float4)
//   KBg[d][q] = {K[d][2q], K[d][2q+1], B[d][2q], B[d][2q+1]} (1280 float4)
//   beta[t]   = (|bw_t|+1e-8)/sum
// ---------------------------------------------------------------------------
__global__ void precompute_kernel(const float* __restrict__ Kg, const float* __restrict__ Bg,
                                  const float* __restrict__ betaw,
                                  float4* __restrict__ Qg, float4* __restrict__ KBg,
                                  float* __restrict__ beta) {
    int job = blockIdx.x * 256 + threadIdx.x;
    if (job < 1600) {
        int d = job / 40, e = job - d * 40;
        const float* kd = Kg + d * 64;
        const float* ke = Kg + e * 64;
        const float* bd = Bg + d * 64;
        const float* be = Bg + e * 64;
        float kk = 0, kbT = 0, kbr = 0, bb = 0;
        for (int u = 0; u < 64; ++u) {
            kk  = fmaf(kd[u], ke[u], kk);
            kbT = fmaf(ke[u], bd[u], kbT);
            kbr = fmaf(kd[u], be[u], kbr);
            bb  = fmaf(bd[u], be[u], bb);
        }
        Qg[job] = make_float4(kk, kbT, kbr, bb);
    } else if (job < 2880) {
        int j2 = job - 1600;
        int d = j2 >> 5, q = j2 & 31;
        KBg[j2] = make_float4(Kg[d * 64 + 2 * q], Kg[d * 64 + 2 * q + 1],
                              Bg[d * 64 + 2 * q], Bg[d * 64 + 2 * q + 1]);
    }
    if (blockIdx.x == 0) {
        int tid = threadIdx.x;
        __shared__ float red[256];
        float av = (tid < 128) ? (fabsf(betaw[tid]) + 1e-8f) : 0.0f;
        red[tid] = av;
        __syncthreads();
        for (int s = 128; s > 0; s >>= 1) {
            if (tid < s) red[tid] += red[tid + s];
            __syncthreads();
        }
        float tot = red[0];
        if (tid < 128) beta[tid] = av / tot;
    }
}

// ---------------------------------------------------------------------------
// Kernel B: one LSTM layer (gates i,f,g,o). One 512-thread block per batch
// row, K-split: half-blocks each compute half the gate dot-product.
// ---------------------------------------------------------------------------
template <int DIN>
__launch_bounds__(512, 2)
__global__ void lstm_kernel(const float* __restrict__ xin, const float* __restrict__ W,
                            const float* __restrict__ U, const float* __restrict__ bvec,
                            float* __restrict__ hout) {
    constexpr int HD = DIN / 2;
    int b = blockIdx.x;
    int tid = threadIdx.x;
    int j = tid & 255;
    int half = tid >> 8;
    int lane = tid & 63;
    int hb = __builtin_amdgcn_readfirstlane(tid) >> 8;  // wave-uniform half id

    float wcol[HD];
    float ucol[32];
#pragma unroll
    for (int d = 0; d < HD; ++d) wcol[d] = W[(half * HD + d) * 256 + j];
#pragma unroll
    for (int k = 0; k < 32; ++k) ucol[k] = U[(half * 32 + k) * 256 + j];
    float bj = (tid < 256) ? bvec[j] : 0.0f;

    __shared__ float x_lds[128 * DIN];
    __shared__ float part[512];
    __shared__ float a_lds[256];
    __shared__ float h_lds[64];
    const float4* xg = (const float4*)(xin + (size_t)b * 128 * DIN);
    float4* xl = (float4*)x_lds;
    for (int i = tid; i < 128 * DIN / 4; i += 512) xl[i] = xg[i];
    if (tid < 64) h_lds[tid] = 0.0f;
    float c = 0.0f;
    __syncthreads();

    int li = (lane < DIN) ? lane : 0;
    for (int t = 0; t < 128; ++t) {
        float xv = x_lds[t * DIN + li];
        float hv = h_lds[lane];
        float a0 = 0.0f, a1 = 0.0f;
        if (hb == 0) {
#pragma unroll
            for (int d = 0; d < HD; d += 2) {
                a0 = fmaf(rlane(xv, d), wcol[d], a0);
                a1 = fmaf(rlane(xv, d + 1), wcol[d + 1], a1);
            }
#pragma unroll
            for (int k = 0; k < 32; k += 2) {
                a0 = fmaf(rlane(hv, k), ucol[k], a0);
                a1 = fmaf(rlane(hv, k + 1), ucol[k + 1], a1);
            }
        } else {
#pragma unroll
            for (int d = 0; d < HD; d += 2) {
                a0 = fmaf(rlane(xv, HD + d), wcol[d], a0);
                a1 = fmaf(rlane(xv, HD + d + 1), wcol[d + 1], a1);
            }
#pragma unroll
            for (int k = 0; k < 32; k += 2) {
                a0 = fmaf(rlane(hv, 32 + k), ucol[k], a0);
                a1 = fmaf(rlane(hv, 32 + k + 1), ucol[k + 1], a1);
            }
        }
        part[tid] = a0 + a1;
        __syncthreads();
        if (tid < 256) {
            float acc = part[tid] + part[tid + 256] + bj;
            int g = tid >> 6;
            float a = (g == 2) ? tanh_f(acc) : sigf(acc);
            a_lds[tid] = a;
        }
        __syncthreads();
        if (tid < 64) {
            float iv = a_lds[tid], fv = a_lds[tid + 64];
            float gv = a_lds[tid + 128], ov = a_lds[tid + 192];
            c = fmaf(fv, c, iv * gv);
            float h = ov * tanh_f(c);
            h_lds[tid] = h;
            hout[((size_t)b * 128 + t) * 64 + tid] = h;
        }
        __syncthreads();
    }
}

// ---------------------------------------------------------------------------
// Kernel C: attention. One wave per 8 (b,t): quad-table G build, register GE
// solve, then only accumulate ws=Σβ·x·α, as=Σβ·α; the o_hat matvec is
// done ONCE per block at the end. Grid = 1024 blocks x 256 thr (4 waves).
// ---------------------------------------------------------------------------
__launch_bounds__(256, 3)
__global__ void attn_kernel(const float* __restrict__ xin, const float* __restrict__ yin,
                            const float4* __restrict__ Qg, const float4* __restrict__ KBg,
                            const float* __restrict__ betap, float* __restrict__ zpart) {
    __shared__ float4 sQ4[40 * 41];   // G-build quads, stride 41 (26.2 KB)
    __shared__ float4 sKB4[40 * 33];  // K/B pair quads, stride 33 (21.1 KB)
    __shared__ float redW[4][64];
    __shared__ float redA[4][64];
    __shared__ float wsf[64];
    __shared__ float asf[64];
    int tid = threadIdx.x;
    for (int i = tid; i < 1600; i += 256) {
        int d = i / 40, e = i - d * 40;
        sQ4[d * 41 + e] = Qg[i];
    }
    for (int i = tid; i < 1280; i += 256) {
        int d = i >> 5, q = i & 31;
        sKB4[d * 33 + q] = KBg[i];
    }
    __syncthreads();

    int b = blockIdx.x >> 2;
    int qq = blockIdx.x & 3;
    int wv = tid >> 6;
    int lane = tid & 63;
    int rl0 = (lane < 40) ? lane : 39;
    const float4* Qrow = sQ4 + rl0 * 41;
    const float4* KBrow = sKB4 + rl0 * 33;

    float wsacc = 0.0f, asacc = 0.0f;
    int t0 = qq * 32 + wv * 8;
    size_t bt0 = (size_t)b * 128 + t0;
    float xp = xin[bt0 * 40 + rl0];
    float yp = yin[bt0 * 64 + lane];

#pragma unroll 1
    for (int it = 0; it < 8; ++it) {
        float xv = (lane < 40) ? xp : 0.0f;
        float yv = yp;
        float betat = betap[t0 + it];
        if (it < 7) {
            size_t btn = bt0 + it + 1;
            xp = xin[btn * 40 + rl0];
            yp = yin[btn * 64 + lane];
        }

        // t1 = (K y)_d, t2 = (B y)_d  (lane = row d), quad-vectorized
        float t1a = 0, t1b = 0, t2a = 0, t2b = 0;
#pragma unroll
        for (int q = 0; q < 32; ++q) {
            float4 kb = KBrow[q];
            float y0 = rlane(yv, 2 * q);
            float y1 = rlane(yv, 2 * q + 1);
            t1a = fmaf(kb.x, y0, t1a);
            t1b = fmaf(kb.y, y1, t1b);
            t2a = fmaf(kb.z, y0, t2a);
            t2b = fmaf(kb.w, y1, t2b);
        }

        // Augmented row: A[e] = G[d][e], A[40] = (F y)_d
        float A[41];
        A[40] = fmaf(xv, t1a + t1b, t2a + t2b);
#pragma unroll
        for (int e = 0; e < 40; ++e) {
            float4 q4 = Qrow[e];
            float f1 = fmaf(xv, q4.x, q4.y);
            float f2 = fmaf(xv, q4.z, q4.w);
            A[e] = fmaf(rlane(xv, e), f1, f2);
        }

        // GE forward elimination (PD Gram, no pivoting), rcp pivots
        float rpl = 0.0f;
#pragma unroll
        for (int k = 0; k < 40; ++k) {
            float piv = rlane(A[k], k);
            float rp = __builtin_amdgcn_rcpf(piv);
            rpl = (lane == k) ? rp : rpl;
            float m = (lane > k) ? A[k] * rp : 0.0f;
#pragma unroll
            for (int j = k + 1; j <= 40; ++j) {
                A[j] = fmaf(-m, rlane(A[j], k), A[j]);
            }
        }

        // Back substitution (division-free)
        float acc = A[40];
        float alpha = 0.0f;
#pragma unroll
        for (int k = 39; k >= 0; --k) {
            float xk = rlane(acc, k) * rlane(rpl, k);
            alpha = (lane == k) ? xk : alpha;
            acc = fmaf(-xk, A[k], acc);
        }

        // Deferred o_hat: just accumulate beta-weighted alpha terms
        wsacc = fmaf(betat, alpha * xv, wsacc);
        asacc = fmaf(betat, alpha, asacc);
    }

    redW[wv][lane] = wsacc;
    redA[wv][lane] = asacc;
    __syncthreads();
    if (tid < 64) {
        wsf[tid] = (redW[0][tid] + redW[1][tid]) + (redW[2][tid] + redW[3][tid]);
    } else if (tid < 128) {
        int d = tid - 64;
        asf[d] = (redA[0][d] + redA[1][d]) + (redA[2][d] + redA[3][d]);
    }
    __syncthreads();
    if (tid < 64) {
        // z[u] = sum_d wsf[d]*K[d][u] + asf[d]*B[d][u]
        const float* KBf = (const float*)sKB4;
        int u = tid;
        int off = ((u >> 1) << 2) + (u & 1);
        float z = 0.0f;
#pragma unroll
        for (int d = 0; d < 40; ++d) {
            float kv = KBf[d * 132 + off];
            float bv = KBf[d * 132 + off + 2];
            z = fmaf(wsf[d], kv, z);
            z = fmaf(asf[d], bv, z);
        }
        zpart[((size_t)b * 4 + qq) * 64 + u] = z;
    }
}

// ---------------------------------------------------------------------------
// Kernel D: deterministic final reduce over the 4 quarter-blocks per b.
// ---------------------------------------------------------------------------
__global__ void reduce_kernel(const float* __restrict__ zpart, float* __restrict__ out) {
    int idx = blockIdx.x * 256 + threadIdx.x;  // 16384 = 256*64
    int b = idx >> 6, u = idx & 63;
    const float* zp = zpart + (size_t)b * 4 * 64 + u;
    out[idx] = (zp[0] + zp[64]) + (zp[128] + zp[192]);
}

// ---------------------------------------------------------------------------
extern "C" void kernel_launch(void* const* d_in, const int* in_sizes, int n_in,
                              void* d_out, int out_size, void* d_ws, size_t ws_size,
                              hipStream_t stream) {
    const float* x  = (const float*)d_in[0];
    const float* W0 = (const float*)d_in[1];
    const float* U0 = (const float*)d_in[2];
    const float* b0 = (const float*)d_in[3];
    const float* W1 = (const float*)d_in[4];
    const float* U1 = (const float*)d_in[5];
    const float* b1 = (const float*)d_in[6];
    const float* Kg = (const float*)d_in[7];
    const float* Bg = (const float*)d_in[8];
    const float* bw = (const float*)d_in[9];
    float* out = (float*)d_out;

    float* h0    = (float*)d_ws;             // 2,097,152 f32 (reused as zpart later)
    float* y     = h0 + 256 * 128 * 64;      // 2,097,152 f32
    float4* Qg   = (float4*)(y + 256 * 128 * 64);  // 1600 float4
    float4* KBg  = Qg + 1600;                // 1280 float4
    float* beta  = (float*)(KBg + 1280);     // 128 f32
    float* zpart = h0;                       // 65,536 f32, overlays h0 (dead by then)

    precompute_kernel<<<12, 256, 0, stream>>>(Kg, Bg, bw, Qg, KBg, beta);
    lstm_kernel<40><<<256, 512, 0, stream>>>(x, W0, U0, b0, h0);
    lstm_kernel<64><<<256, 512, 0, stream>>>(h0, W1, U1, b1, y);
    attn_kernel<<<1024, 256, 0, stream>>>(x, y, Qg, KBg, beta, zpart);
    reduce_kernel<<<64, 256, 0, stream>>>(zpart, out);
}

// Round 4
// 634.272 us; speedup vs baseline: 1.5454x; 1.0556x over previous
//
#include <hip/hip_runtime.h>
#include <math.h>

#define DEVI __device__ __forceinline__

DEVI float rlane(float v, int l) {
    return __builtin_bit_cast(float, __builtin_amdgcn_readlane(__builtin_bit_cast(int, v), l));
}
DEVI float sigf(float v) { return 1.0f / (1.0f + __expf(-v)); }
DEVI float tanh_f(float v) {
    v = fminf(fmaxf(v, -15.0f), 15.0f);
    float e = __expf(2.0f * v);
    return (e - 1.0f) / (e + 1.0f);
}
DEVI float4 rlane4(float4 v, int l) {
    return make_float4(rlane(v.x, l), rlane(v.y, l), rlane(v.z, l), rlane(v.w, l));
}

// ---------------------------------------------------------------------------
// Kernel A: fused (b,t)-independent tables.
//   Qg[d*40+e]  = {kk[d][e], kb[e][d], kb[d][e], bb[d][e]}
//   KBg[d*32+q] = {K[d][2q], K[d][2q+1], B[d][2q], B[d][2q+1]}
//   beta[t]     = (|bw_t|+1e-8)/sum
// ---------------------------------------------------------------------------
__global__ void precompute_kernel(const float* __restrict__ Kg, const float* __restrict__ Bg,
                                  const float* __restrict__ betaw,
                                  float4* __restrict__ Qg, float4* __restrict__ KBg,
                                  float* __restrict__ beta) {
    int job = blockIdx.x * 256 + threadIdx.x;
    if (job < 1600) {
        int d = job / 40, e = job - d * 40;
        const float* kd = Kg + d * 64;
        const float* ke = Kg + e * 64;
        const float* bd = Bg + d * 64;
        const float* be = Bg + e * 64;
        float kk = 0, kbT = 0, kbr = 0, bb = 0;
        for (int u = 0; u < 64; ++u) {
            kk  = fmaf(kd[u], ke[u], kk);
            kbT = fmaf(ke[u], bd[u], kbT);
            kbr = fmaf(kd[u], be[u], kbr);
            bb  = fmaf(bd[u], be[u], bb);
        }
        Qg[job] = make_float4(kk, kbT, kbr, bb);
    } else if (job < 2880) {
        int j2 = job - 1600;
        int d = j2 >> 5, q = j2 & 31;
        KBg[j2] = make_float4(Kg[d * 64 + 2 * q], Kg[d * 64 + 2 * q + 1],
                              Bg[d * 64 + 2 * q], Bg[d * 64 + 2 * q + 1]);
    }
    if (blockIdx.x == 0) {
        int tid = threadIdx.x;
        __shared__ float red[256];
        float av = (tid < 128) ? (fabsf(betaw[tid]) + 1e-8f) : 0.0f;
        red[tid] = av;
        __syncthreads();
        for (int s = 128; s > 0; s >>= 1) {
            if (tid < s) red[tid] += red[tid + s];
            __syncthreads();
        }
        float tot = red[0];
        if (tid < 128) beta[tid] = av / tot;
    }
}

// ---------------------------------------------------------------------------
// Kernel B: one LSTM layer (gates i,f,g,o). One 512-thread block per batch
// row, K-split halves; 4 accumulators for issue-chain ILP.
// ---------------------------------------------------------------------------
template <int DIN>
__launch_bounds__(512, 2)
__global__ void lstm_kernel(const float* __restrict__ xin, const float* __restrict__ W,
                            const float* __restrict__ U, const float* __restrict__ bvec,
                            float* __restrict__ hout) {
    constexpr int HD = DIN / 2;
    int b = blockIdx.x;
    int tid = threadIdx.x;
    int j = tid & 255;
    int half = tid >> 8;
    int lane = tid & 63;
    int hb = __builtin_amdgcn_readfirstlane(tid) >> 8;

    float wcol[HD];
    float ucol[32];
#pragma unroll
    for (int d = 0; d < HD; ++d) wcol[d] = W[(half * HD + d) * 256 + j];
#pragma unroll
    for (int k = 0; k < 32; ++k) ucol[k] = U[(half * 32 + k) * 256 + j];
    float bj = (tid < 256) ? bvec[j] : 0.0f;

    __shared__ float x_lds[128 * DIN];
    __shared__ float part[512];
    __shared__ float a_lds[256];
    __shared__ float h_lds[64];
    const float4* xg = (const float4*)(xin + (size_t)b * 128 * DIN);
    float4* xl = (float4*)x_lds;
    for (int i = tid; i < 128 * DIN / 4; i += 512) xl[i] = xg[i];
    if (tid < 64) h_lds[tid] = 0.0f;
    float c = 0.0f;
    __syncthreads();

    int li = (lane < DIN) ? lane : 0;
    int xoff = hb * HD;
    int hoff = hb * 32;
    for (int t = 0; t < 128; ++t) {
        float xv = x_lds[t * DIN + li];
        float hv = h_lds[lane];
        float a0 = 0.0f, a1 = 0.0f, a2 = 0.0f, a3 = 0.0f;
#pragma unroll
        for (int d = 0; d < HD; d += 4) {
            a0 = fmaf(rlane(xv, xoff + d), wcol[d], a0);
            a1 = fmaf(rlane(xv, xoff + d + 1), wcol[d + 1], a1);
            a2 = fmaf(rlane(xv, xoff + d + 2), wcol[d + 2], a2);
            a3 = fmaf(rlane(xv, xoff + d + 3), wcol[d + 3], a3);
        }
#pragma unroll
        for (int k = 0; k < 32; k += 4) {
            a0 = fmaf(rlane(hv, hoff + k), ucol[k], a0);
            a1 = fmaf(rlane(hv, hoff + k + 1), ucol[k + 1], a1);
            a2 = fmaf(rlane(hv, hoff + k + 2), ucol[k + 2], a2);
            a3 = fmaf(rlane(hv, hoff + k + 3), ucol[k + 3], a3);
        }
        part[tid] = (a0 + a1) + (a2 + a3);
        __syncthreads();
        if (tid < 256) {
            float acc = part[tid] + part[tid + 256] + bj;
            int g = tid >> 6;
            float a = (g == 2) ? tanh_f(acc) : sigf(acc);
            a_lds[tid] = a;
        }
        __syncthreads();
        if (tid < 64) {
            float iv = a_lds[tid], fv = a_lds[tid + 64];
            float gv = a_lds[tid + 128], ov = a_lds[tid + 192];
            c = fmaf(fv, c, iv * gv);
            float h = ov * tanh_f(c);
            h_lds[tid] = h;
            hout[((size_t)b * 128 + t) * 64 + tid] = h;
        }
        __syncthreads();
    }
}

// ---------------------------------------------------------------------------
// Kernel C: attention. 4 solves per wave (float4 stream layout) for 8
// independent issue chains per SIMD at 2 waves/SIMD. Table LDS reads shared
// across the 4 streams. Deferred o_hat. Grid 512 x 256 (half-b per block).
// ---------------------------------------------------------------------------
__launch_bounds__(256)
__global__ void attn_kernel(const float* __restrict__ xin, const float* __restrict__ yin,
                            const float4* __restrict__ Qg, const float4* __restrict__ KBg,
                            const float* __restrict__ betap, float* __restrict__ zpart) {
    __shared__ float4 sQ4[40 * 41];   // 26.2 KB
    __shared__ float4 sKB4[40 * 33];  // 21.1 KB
    __shared__ float redW[4][64];
    __shared__ float redA[4][64];
    __shared__ float wsf[64];
    __shared__ float asf[64];
    int tid = threadIdx.x;
    for (int i = tid; i < 1600; i += 256) {
        int d = i / 40, e = i - d * 40;
        sQ4[d * 41 + e] = Qg[i];
    }
    for (int i = tid; i < 1280; i += 256) {
        int d = i >> 5, q = i & 31;
        sKB4[d * 33 + q] = KBg[i];
    }
    __syncthreads();

    int b = blockIdx.x >> 1;
    int half = blockIdx.x & 1;
    int wv = tid >> 6;
    int lane = tid & 63;
    int rl0 = (lane < 40) ? lane : 39;
    const float4* Qrow = sQ4 + rl0 * 41;
    const float4* KBrow = sKB4 + rl0 * 33;

    float4 wsacc = make_float4(0.f, 0.f, 0.f, 0.f);
    float4 asacc = make_float4(0.f, 0.f, 0.f, 0.f);
    int t0 = half * 64 + wv * 16;
    size_t bt0 = (size_t)b * 128 + t0;

#pragma unroll 1
    for (int it = 0; it < 4; ++it) {
        size_t g0 = bt0 + it * 4;
        float4 xv, yv, bt4;
        xv.x = xin[(g0 + 0) * 40 + rl0];
        xv.y = xin[(g0 + 1) * 40 + rl0];
        xv.z = xin[(g0 + 2) * 40 + rl0];
        xv.w = xin[(g0 + 3) * 40 + rl0];
        yv.x = yin[(g0 + 0) * 64 + lane];
        yv.y = yin[(g0 + 1) * 64 + lane];
        yv.z = yin[(g0 + 2) * 64 + lane];
        yv.w = yin[(g0 + 3) * 64 + lane];
        bt4.x = betap[t0 + it * 4 + 0];
        bt4.y = betap[t0 + it * 4 + 1];
        bt4.z = betap[t0 + it * 4 + 2];
        bt4.w = betap[t0 + it * 4 + 3];
        if (lane >= 40) xv = make_float4(0.f, 0.f, 0.f, 0.f);

        // t1 = (K y)_d, t2 = (B y)_d per stream; table quad shared by streams
        float4 t1a = make_float4(0.f, 0.f, 0.f, 0.f), t1b = t1a, t2a = t1a, t2b = t1a;
#pragma unroll
        for (int q = 0; q < 32; ++q) {
            float4 kb = KBrow[q];
            float4 y0 = rlane4(yv, 2 * q);
            float4 y1 = rlane4(yv, 2 * q + 1);
            t1a.x = fmaf(kb.x, y0.x, t1a.x); t1a.y = fmaf(kb.x, y0.y, t1a.y);
            t1a.z = fmaf(kb.x, y0.z, t1a.z); t1a.w = fmaf(kb.x, y0.w, t1a.w);
            t1b.x = fmaf(kb.y, y1.x, t1b.x); t1b.y = fmaf(kb.y, y1.y, t1b.y);
            t1b.z = fmaf(kb.y, y1.z, t1b.z); t1b.w = fmaf(kb.y, y1.w, t1b.w);
            t2a.x = fmaf(kb.z, y0.x, t2a.x); t2a.y = fmaf(kb.z, y0.y, t2a.y);
            t2a.z = fmaf(kb.z, y0.z, t2a.z); t2a.w = fmaf(kb.z, y0.w, t2a.w);
            t2b.x = fmaf(kb.w, y1.x, t2b.x); t2b.y = fmaf(kb.w, y1.y, t2b.y);
            t2b.z = fmaf(kb.w, y1.z, t2b.z); t2b.w = fmaf(kb.w, y1.w, t2b.w);
        }

        float4 A[41];
        A[40].x = fmaf(xv.x, t1a.x + t1b.x, t2a.x + t2b.x);
        A[40].y = fmaf(xv.y, t1a.y + t1b.y, t2a.y + t2b.y);
        A[40].z = fmaf(xv.z, t1a.z + t1b.z, t2a.z + t2b.z);
        A[40].w = fmaf(xv.w, t1a.w + t1b.w, t2a.w + t2b.w);
#pragma unroll
        for (int e = 0; e < 40; ++e) {
            float4 q4 = Qrow[e];
            float4 sxe = rlane4(xv, e);
            A[e].x = fmaf(sxe.x, fmaf(xv.x, q4.x, q4.y), fmaf(xv.x, q4.z, q4.w));
            A[e].y = fmaf(sxe.y, fmaf(xv.y, q4.x, q4.y), fmaf(xv.y, q4.z, q4.w));
            A[e].z = fmaf(sxe.z, fmaf(xv.z, q4.x, q4.y), fmaf(xv.z, q4.z, q4.w));
            A[e].w = fmaf(sxe.w, fmaf(xv.w, q4.x, q4.y), fmaf(xv.w, q4.z, q4.w));
        }

        // GE forward elimination (PD Gram, no pivoting), 4 streams interleaved
        float4 rpl = make_float4(0.f, 0.f, 0.f, 0.f);
#pragma unroll
        for (int k = 0; k < 40; ++k) {
            float4 piv = rlane4(A[k], k);
            float4 rp;
            rp.x = __builtin_amdgcn_rcpf(piv.x);
            rp.y = __builtin_amdgcn_rcpf(piv.y);
            rp.z = __builtin_amdgcn_rcpf(piv.z);
            rp.w = __builtin_amdgcn_rcpf(piv.w);
            bool eq = (lane == k);
            rpl.x = eq ? rp.x : rpl.x; rpl.y = eq ? rp.y : rpl.y;
            rpl.z = eq ? rp.z : rpl.z; rpl.w = eq ? rp.w : rpl.w;
            bool gt = (lane > k);
            float4 m;
            m.x = gt ? A[k].x * rp.x : 0.f;
            m.y = gt ? A[k].y * rp.y : 0.f;
            m.z = gt ? A[k].z * rp.z : 0.f;
            m.w = gt ? A[k].w * rp.w : 0.f;
#pragma unroll
            for (int jj = k + 1; jj <= 40; ++jj) {
                float4 r = rlane4(A[jj], k);
                A[jj].x = fmaf(-m.x, r.x, A[jj].x);
                A[jj].y = fmaf(-m.y, r.y, A[jj].y);
                A[jj].z = fmaf(-m.z, r.z, A[jj].z);
                A[jj].w = fmaf(-m.w, r.w, A[jj].w);
            }
        }

        // Back substitution (division-free)
        float4 acc = A[40];
        float4 alpha = make_float4(0.f, 0.f, 0.f, 0.f);
#pragma unroll
        for (int k = 39; k >= 0; --k) {
            float4 na = rlane4(acc, k);
            float4 rk = rlane4(rpl, k);
            float4 xk = make_float4(na.x * rk.x, na.y * rk.y, na.z * rk.z, na.w * rk.w);
            bool eq = (lane == k);
            alpha.x = eq ? xk.x : alpha.x; alpha.y = eq ? xk.y : alpha.y;
            alpha.z = eq ? xk.z : alpha.z; alpha.w = eq ? xk.w : alpha.w;
            acc.x = fmaf(-xk.x, A[k].x, acc.x);
            acc.y = fmaf(-xk.y, A[k].y, acc.y);
            acc.z = fmaf(-xk.z, A[k].z, acc.z);
            acc.w = fmaf(-xk.w, A[k].w, acc.w);
        }

        wsacc.x = fmaf(bt4.x, alpha.x * xv.x, wsacc.x);
        wsacc.y = fmaf(bt4.y, alpha.y * xv.y, wsacc.y);
        wsacc.z = fmaf(bt4.z, alpha.z * xv.z, wsacc.z);
        wsacc.w = fmaf(bt4.w, alpha.w * xv.w, wsacc.w);
        asacc.x = fmaf(bt4.x, alpha.x, asacc.x);
        asacc.y = fmaf(bt4.y, alpha.y, asacc.y);
        asacc.z = fmaf(bt4.z, alpha.z, asacc.z);
        asacc.w = fmaf(bt4.w, alpha.w, asacc.w);
    }

    redW[wv][lane] = (wsacc.x + wsacc.y) + (wsacc.z + wsacc.w);
    redA[wv][lane] = (asacc.x + asacc.y) + (asacc.z + asacc.w);
    __syncthreads();
    if (tid < 64) {
        wsf[tid] = (redW[0][tid] + redW[1][tid]) + (redW[2][tid] + redW[3][tid]);
    } else if (tid < 128) {
        int d = tid - 64;
        asf[d] = (redA[0][d] + redA[1][d]) + (redA[2][d] + redA[3][d]);
    }
    __syncthreads();
    if (tid < 64) {
        const float* KBf = (const float*)sKB4;
        int u = tid;
        int off = ((u >> 1) << 2) + (u & 1);
        float z = 0.0f;
#pragma unroll
        for (int d = 0; d < 40; ++d) {
            float kv = KBf[d * 132 + off];
            float bv = KBf[d * 132 + off + 2];
            z = fmaf(wsf[d], kv, z);
            z = fmaf(asf[d], bv, z);
        }
        zpart[((size_t)b * 2 + half) * 64 + u] = z;
    }
}

// ---------------------------------------------------------------------------
// Kernel D: deterministic final reduce over the 2 half-blocks per b.
// ---------------------------------------------------------------------------
__global__ void reduce_kernel(const float* __restrict__ zpart, float* __restrict__ out) {
    int idx = blockIdx.x * 256 + threadIdx.x;  // 16384 = 256*64
    int b = idx >> 6, u = idx & 63;
    const float* zp = zpart + (size_t)b * 2 * 64 + u;
    out[idx] = zp[0] + zp[64];
}

// ---------------------------------------------------------------------------
extern "C" void kernel_launch(void* const* d_in, const int* in_sizes, int n_in,
                              void* d_out, int out_size, void* d_ws, size_t ws_size,
                              hipStream_t stream) {
    const float* x  = (const float*)d_in[0];
    const float* W0 = (const float*)d_in[1];
    const float* U0 = (const float*)d_in[2];
    const float* b0 = (const float*)d_in[3];
    const float* W1 = (const float*)d_in[4];
    const float* U1 = (const float*)d_in[5];
    const float* b1 = (const float*)d_in[6];
    const float* Kg = (const float*)d_in[7];
    const float* Bg = (const float*)d_in[8];
    const float* bw = (const float*)d_in[9];
    float* out = (float*)d_out;

    float* h0    = (float*)d_ws;                   // 2,097,152 f32
    float* y     = h0 + 256 * 128 * 64;            // 2,097,152 f32
    float4* Qg   = (float4*)(y + 256 * 128 * 64);  // 1600 float4
    float4* KBg  = Qg + 1600;                      // 1280 float4
    float* beta  = (float*)(KBg + 1280);           // 128 f32
    float* zpart = h0;                             // 32,768 f32, overlays h0 (dead)

    precompute_kernel<<<12, 256, 0, stream>>>(Kg, Bg, bw, Qg, KBg, beta);
    lstm_kernel<40><<<256, 512, 0, stream>>>(x, W0, U0, b0, h0);
    lstm_kernel<64><<<256, 512, 0, stream>>>(h0, W1, U1, b1, y);
    attn_kernel<<<512, 256, 0, stream>>>(x, y, Qg, KBg, beta, zpart);
    reduce_kernel<<<64, 256, 0, stream>>>(zpart, out);
}

// Round 5
// 445.482 us; speedup vs baseline: 2.2004x; 1.4238x over previous
//
#include <hip/hip_runtime.h>
#include <math.h>

#define DEVI __device__ __forceinline__

DEVI float rlane(float v, int l) {
    return __builtin_bit_cast(float, __builtin_amdgcn_readlane(__builtin_bit_cast(int, v), l));
}
DEVI float2 rlane2(float2 v, int l) {
    return make_float2(rlane(v.x, l), rlane(v.y, l));
}
DEVI float sigf(float v) { return 1.0f / (1.0f + __expf(-v)); }
DEVI float tanh_f(float v) {
    v = fminf(fmaxf(v, -15.0f), 15.0f);
    float e = __expf(2.0f * v);
    return (e - 1.0f) / (e + 1.0f);
}

// ---------------------------------------------------------------------------
// Kernel A: fused (b,t)-independent tables.
//   Qg[d*40+e]  = {kk[d][e], kb[e][d], kb[d][e], bb[d][e]}
//   KBg[d*32+q] = {K[d][2q], K[d][2q+1], B[d][2q], B[d][2q+1]}
//   beta[t]     = (|bw_t|+1e-8)/sum
// ---------------------------------------------------------------------------
__global__ void precompute_kernel(const float* __restrict__ Kg, const float* __restrict__ Bg,
                                  const float* __restrict__ betaw,
                                  float4* __restrict__ Qg, float4* __restrict__ KBg,
                                  float* __restrict__ beta) {
    int job = blockIdx.x * 256 + threadIdx.x;
    if (job < 1600) {
        int d = job / 40, e = job - d * 40;
        const float* kd = Kg + d * 64;
        const float* ke = Kg + e * 64;
        const float* bd = Bg + d * 64;
        const float* be = Bg + e * 64;
        float kk = 0, kbT = 0, kbr = 0, bb = 0;
        for (int u = 0; u < 64; ++u) {
            kk  = fmaf(kd[u], ke[u], kk);
            kbT = fmaf(ke[u], bd[u], kbT);
            kbr = fmaf(kd[u], be[u], kbr);
            bb  = fmaf(bd[u], be[u], bb);
        }
        Qg[job] = make_float4(kk, kbT, kbr, bb);
    } else if (job < 2880) {
        int j2 = job - 1600;
        int d = j2 >> 5, q = j2 & 31;
        KBg[j2] = make_float4(Kg[d * 64 + 2 * q], Kg[d * 64 + 2 * q + 1],
                              Bg[d * 64 + 2 * q], Bg[d * 64 + 2 * q + 1]);
    }
    if (blockIdx.x == 0) {
        int tid = threadIdx.x;
        __shared__ float red[256];
        float av = (tid < 128) ? (fabsf(betaw[tid]) + 1e-8f) : 0.0f;
        red[tid] = av;
        __syncthreads();
        for (int s = 128; s > 0; s >>= 1) {
            if (tid < s) red[tid] += red[tid + s];
            __syncthreads();
        }
        float tot = red[0];
        if (tid < 128) beta[tid] = av / tot;
    }
}

// ---------------------------------------------------------------------------
// Kernel B: one LSTM layer (gates i,f,g,o). One 512-thread block per batch
// row, K-split halves with compile-time broadcast lanes; 4 accumulators.
// ---------------------------------------------------------------------------
template <int DIN>
__launch_bounds__(512, 2)
__global__ void lstm_kernel(const float* __restrict__ xin, const float* __restrict__ W,
                            const float* __restrict__ U, const float* __restrict__ bvec,
                            float* __restrict__ hout) {
    constexpr int HD = DIN / 2;
    int b = blockIdx.x;
    int tid = threadIdx.x;
    int j = tid & 255;
    int half = tid >> 8;
    int lane = tid & 63;
    int hb = __builtin_amdgcn_readfirstlane(tid) >> 8;  // wave-uniform half id

    float wcol[HD];
    float ucol[32];
#pragma unroll
    for (int d = 0; d < HD; ++d) wcol[d] = W[(half * HD + d) * 256 + j];
#pragma unroll
    for (int k = 0; k < 32; ++k) ucol[k] = U[(half * 32 + k) * 256 + j];
    float bj = (tid < 256) ? bvec[j] : 0.0f;

    __shared__ float x_lds[128 * DIN];
    __shared__ float part[512];
    __shared__ float a_lds[256];
    __shared__ float h_lds[64];
    const float4* xg = (const float4*)(xin + (size_t)b * 128 * DIN);
    float4* xl = (float4*)x_lds;
    for (int i = tid; i < 128 * DIN / 4; i += 512) xl[i] = xg[i];
    if (tid < 64) h_lds[tid] = 0.0f;
    float c = 0.0f;
    __syncthreads();

    int li = (lane < DIN) ? lane : 0;
    for (int t = 0; t < 128; ++t) {
        float xv = x_lds[t * DIN + li];
        float hv = h_lds[lane];
        float a0 = 0.0f, a1 = 0.0f, a2 = 0.0f, a3 = 0.0f;
        if (hb == 0) {
#pragma unroll
            for (int d = 0; d < HD; d += 4) {
                a0 = fmaf(rlane(xv, d), wcol[d], a0);
                a1 = fmaf(rlane(xv, d + 1), wcol[d + 1], a1);
                a2 = fmaf(rlane(xv, d + 2), wcol[d + 2], a2);
                a3 = fmaf(rlane(xv, d + 3), wcol[d + 3], a3);
            }
#pragma unroll
            for (int k = 0; k < 32; k += 4) {
                a0 = fmaf(rlane(hv, k), ucol[k], a0);
                a1 = fmaf(rlane(hv, k + 1), ucol[k + 1], a1);
                a2 = fmaf(rlane(hv, k + 2), ucol[k + 2], a2);
                a3 = fmaf(rlane(hv, k + 3), ucol[k + 3], a3);
            }
        } else {
#pragma unroll
            for (int d = 0; d < HD; d += 4) {
                a0 = fmaf(rlane(xv, HD + d), wcol[d], a0);
                a1 = fmaf(rlane(xv, HD + d + 1), wcol[d + 1], a1);
                a2 = fmaf(rlane(xv, HD + d + 2), wcol[d + 2], a2);
                a3 = fmaf(rlane(xv, HD + d + 3), wcol[d + 3], a3);
            }
#pragma unroll
            for (int k = 0; k < 32; k += 4) {
                a0 = fmaf(rlane(hv, 32 + k), ucol[k], a0);
                a1 = fmaf(rlane(hv, 32 + k + 1), ucol[k + 1], a1);
                a2 = fmaf(rlane(hv, 32 + k + 2), ucol[k + 2], a2);
                a3 = fmaf(rlane(hv, 32 + k + 3), ucol[k + 3], a3);
            }
        }
        part[tid] = (a0 + a1) + (a2 + a3);
        __syncthreads();
        if (tid < 256) {
            float acc = part[tid] + part[tid + 256] + bj;
            int g = tid >> 6;
            float a = (g == 2) ? tanh_f(acc) : sigf(acc);
            a_lds[tid] = a;
        }
        __syncthreads();
        if (tid < 64) {
            float iv = a_lds[tid], fv = a_lds[tid + 64];
            float gv = a_lds[tid + 128], ov = a_lds[tid + 192];
            c = fmaf(fv, c, iv * gv);
            float h = ov * tanh_f(c);
            h_lds[tid] = h;
            hout[((size_t)b * 128 + t) * 64 + tid] = h;
        }
        __syncthreads();
    }
}

// ---------------------------------------------------------------------------
// Kernel C: attention. 2 solves per wave (float2 streams) -> 4 independent
// issue chains per SIMD at 2 waves/SIMD, spill-free (~145 live VGPRs).
// Table LDS reads shared across both streams. Deferred o_hat.
// Grid 512 x 256 (half-b per block, 16 t per wave).
// ---------------------------------------------------------------------------
__launch_bounds__(256)
__global__ void attn_kernel(const float* __restrict__ xin, const float* __restrict__ yin,
                            const float4* __restrict__ Qg, const float4* __restrict__ KBg,
                            const float* __restrict__ betap, float* __restrict__ zpart) {
    __shared__ float4 sQ4[40 * 41];   // 26.2 KB
    __shared__ float4 sKB4[40 * 33];  // 21.1 KB
    __shared__ float redW[4][64];
    __shared__ float redA[4][64];
    __shared__ float wsf[64];
    __shared__ float asf[64];
    int tid = threadIdx.x;
    for (int i = tid; i < 1600; i += 256) {
        int d = i / 40, e = i - d * 40;
        sQ4[d * 41 + e] = Qg[i];
    }
    for (int i = tid; i < 1280; i += 256) {
        int d = i >> 5, q = i & 31;
        sKB4[d * 33 + q] = KBg[i];
    }
    __syncthreads();

    int b = blockIdx.x >> 1;
    int half = blockIdx.x & 1;
    int wv = tid >> 6;
    int lane = tid & 63;
    int rl0 = (lane < 40) ? lane : 39;
    const float4* Qrow = sQ4 + rl0 * 41;
    const float4* KBrow = sKB4 + rl0 * 33;

    float2 wsacc = make_float2(0.f, 0.f);
    float2 asacc = make_float2(0.f, 0.f);
    int t0 = half * 64 + wv * 16;
    size_t bt0 = (size_t)b * 128 + t0;

    float2 xp, yp;
    xp.x = xin[(bt0 + 0) * 40 + rl0];
    xp.y = xin[(bt0 + 1) * 40 + rl0];
    yp.x = yin[(bt0 + 0) * 64 + lane];
    yp.y = yin[(bt0 + 1) * 64 + lane];

#pragma unroll 1
    for (int it = 0; it < 8; ++it) {
        float2 xv = xp, yv = yp;
        float2 bt2 = make_float2(betap[t0 + 2 * it], betap[t0 + 2 * it + 1]);
        if (it < 7) {
            size_t gn = bt0 + 2 * it + 2;
            xp.x = xin[(gn + 0) * 40 + rl0];
            xp.y = xin[(gn + 1) * 40 + rl0];
            yp.x = yin[(gn + 0) * 64 + lane];
            yp.y = yin[(gn + 1) * 64 + lane];
        }
        if (lane >= 40) xv = make_float2(0.f, 0.f);

        // t1 = (K y)_d, t2 = (B y)_d per stream; table quads shared
        float2 t1a = make_float2(0.f, 0.f), t1b = t1a, t2a = t1a, t2b = t1a;
#pragma unroll
        for (int q = 0; q < 32; ++q) {
            float4 kb = KBrow[q];
            float2 y0 = rlane2(yv, 2 * q);
            float2 y1 = rlane2(yv, 2 * q + 1);
            t1a.x = fmaf(kb.x, y0.x, t1a.x); t1a.y = fmaf(kb.x, y0.y, t1a.y);
            t1b.x = fmaf(kb.y, y1.x, t1b.x); t1b.y = fmaf(kb.y, y1.y, t1b.y);
            t2a.x = fmaf(kb.z, y0.x, t2a.x); t2a.y = fmaf(kb.z, y0.y, t2a.y);
            t2b.x = fmaf(kb.w, y1.x, t2b.x); t2b.y = fmaf(kb.w, y1.y, t2b.y);
        }

        float2 A[41];
        A[40].x = fmaf(xv.x, t1a.x + t1b.x, t2a.x + t2b.x);
        A[40].y = fmaf(xv.y, t1a.y + t1b.y, t2a.y + t2b.y);
#pragma unroll
        for (int e = 0; e < 40; ++e) {
            float4 q4 = Qrow[e];
            float2 sxe = rlane2(xv, e);
            A[e].x = fmaf(sxe.x, fmaf(xv.x, q4.x, q4.y), fmaf(xv.x, q4.z, q4.w));
            A[e].y = fmaf(sxe.y, fmaf(xv.y, q4.x, q4.y), fmaf(xv.y, q4.z, q4.w));
        }

        // GE forward elimination (PD Gram, no pivoting), 2 streams interleaved
        float2 rpl = make_float2(0.f, 0.f);
#pragma unroll
        for (int k = 0; k < 40; ++k) {
            float2 piv = rlane2(A[k], k);
            float2 rp;
            rp.x = __builtin_amdgcn_rcpf(piv.x);
            rp.y = __builtin_amdgcn_rcpf(piv.y);
            bool eq = (lane == k);
            rpl.x = eq ? rp.x : rpl.x;
            rpl.y = eq ? rp.y : rpl.y;
            bool gt = (lane > k);
            float2 m;
            m.x = gt ? A[k].x * rp.x : 0.f;
            m.y = gt ? A[k].y * rp.y : 0.f;
#pragma unroll
            for (int jj = k + 1; jj <= 40; ++jj) {
                float2 r = rlane2(A[jj], k);
                A[jj].x = fmaf(-m.x, r.x, A[jj].x);
                A[jj].y = fmaf(-m.y, r.y, A[jj].y);
            }
        }

        // Back substitution (division-free)
        float2 acc = A[40];
        float2 alpha = make_float2(0.f, 0.f);
#pragma unroll
        for (int k = 39; k >= 0; --k) {
            float2 na = rlane2(acc, k);
            float2 rk = rlane2(rpl, k);
            float2 xk = make_float2(na.x * rk.x, na.y * rk.y);
            bool eq = (lane == k);
            alpha.x = eq ? xk.x : alpha.x;
            alpha.y = eq ? xk.y : alpha.y;
            acc.x = fmaf(-xk.x, A[k].x, acc.x);
            acc.y = fmaf(-xk.y, A[k].y, acc.y);
        }

        wsacc.x = fmaf(bt2.x, alpha.x * xv.x, wsacc.x);
        wsacc.y = fmaf(bt2.y, alpha.y * xv.y, wsacc.y);
        asacc.x = fmaf(bt2.x, alpha.x, asacc.x);
        asacc.y = fmaf(bt2.y, alpha.y, asacc.y);
    }

    redW[wv][lane] = wsacc.x + wsacc.y;
    redA[wv][lane] = asacc.x + asacc.y;
    __syncthreads();
    if (tid < 64) {
        wsf[tid] = (redW[0][tid] + redW[1][tid]) + (redW[2][tid] + redW[3][tid]);
    } else if (tid < 128) {
        int d = tid - 64;
        asf[d] = (redA[0][d] + redA[1][d]) + (redA[2][d] + redA[3][d]);
    }
    __syncthreads();
    if (tid < 64) {
        const float* KBf = (const float*)sKB4;
        int u = tid;
        int off = ((u >> 1) << 2) + (u & 1);
        float z = 0.0f;
#pragma unroll
        for (int d = 0; d < 40; ++d) {
            float kv = KBf[d * 132 + off];
            float bv = KBf[d * 132 + off + 2];
            z = fmaf(wsf[d], kv, z);
            z = fmaf(asf[d], bv, z);
        }
        zpart[((size_t)b * 2 + half) * 64 + u] = z;
    }
}

// ---------------------------------------------------------------------------
// Kernel D: deterministic final reduce over the 2 half-blocks per b.
// ---------------------------------------------------------------------------
__global__ void reduce_kernel(const float* __restrict__ zpart, float* __restrict__ out) {
    int idx = blockIdx.x * 256 + threadIdx.x;  // 16384 = 256*64
    int b = idx >> 6, u = idx & 63;
    const float* zp = zpart + (size_t)b * 2 * 64 + u;
    out[idx] = zp[0] + zp[64];
}

// ---------------------------------------------------------------------------
extern "C" void kernel_launch(void* const* d_in, const int* in_sizes, int n_in,
                              void* d_out, int out_size, void* d_ws, size_t ws_size,
                              hipStream_t stream) {
    const float* x  = (const float*)d_in[0];
    const float* W0 = (const float*)d_in[1];
    const float* U0 = (const float*)d_in[2];
    const float* b0 = (const float*)d_in[3];
    const float* W1 = (const float*)d_in[4];
    const float* U1 = (const float*)d_in[5];
    const float* b1 = (const float*)d_in[6];
    const float* Kg = (const float*)d_in[7];
    const float* Bg = (const float*)d_in[8];
    const float* bw = (const float*)d_in[9];
    float* out = (float*)d_out;

    float* h0    = (float*)d_ws;                   // 2,097,152 f32
    float* y     = h0 + 256 * 128 * 64;            // 2,097,152 f32
    float4* Qg   = (float4*)(y + 256 * 128 * 64);  // 1600 float4
    float4* KBg  = Qg + 1600;                      // 1280 float4
    float* beta  = (float*)(KBg + 1280);           // 128 f32
    float* zpart = h0;                             // 32,768 f32, overlays h0 (dead)

    precompute_kernel<<<12, 256, 0, stream>>>(Kg, Bg, bw, Qg, KBg, beta);
    lstm_kernel<40><<<256, 512, 0, stream>>>(x, W0, U0, b0, h0);
    lstm_kernel<64><<<256, 512, 0, stream>>>(h0, W1, U1, b1, y);
    attn_kernel<<<512, 256, 0, stream>>>(x, y, Qg, KBg, beta, zpart);
    reduce_kernel<<<64, 256, 0, stream>>>(zpart, out);
}